// Round 1
// baseline (551.135 us; speedup 1.0000x reference)
//
#include <hip/hip_runtime.h>
#include <math.h>
#include <float.h>

#define Hh 512
#define Ww 512
#define HWW (Hh*Ww)
#define NP 262144
#define RR 8

// Record: 8 floats = 32B: {depth, alpha, r, g, b, idx(bits), pid(bits), pad}

__global__ __launch_bounds__(256) void point_kernel(
    const float* __restrict__ positions,
    const float* __restrict__ trivecs,
    const float* __restrict__ densities,
    const float* __restrict__ shs,
    const float* __restrict__ viewm,
    const float* __restrict__ projm,
    const float* __restrict__ campos,
    const float* __restrict__ aabb,
    float* __restrict__ recs,
    int* __restrict__ counts)
{
#pragma clang fp contract(off)
    int n = blockIdx.x * blockDim.x + threadIdx.x;
    if (n >= NP) return;

    float px = positions[n*3+0], py = positions[n*3+1], pz = positions[n*3+2];
    // world = aabb[:3] + p * aabb[3:]  (elementwise f32, no FMA)
    float wx = aabb[0] + px*aabb[3];
    float wy = aabb[1] + py*aabb[4];
    float wz = aabb[2] + pz*aabb[5];

    // ph = [w,1] @ proj  (matrix has zeros/pow2 entries -> order-insensitive)
    float phx = ((wx*projm[0] + wy*projm[4]) + wz*projm[8])  + projm[12];
    float phy = ((wx*projm[1] + wy*projm[5]) + wz*projm[9])  + projm[13];
    float phw = ((wx*projm[3] + wy*projm[7]) + wz*projm[11]) + projm[15];
    float denom = phw + 1e-7f;
    float ndcx = phx / denom;           // true IEEE divide (matches np)
    float ndcy = phy / denom;
    float depth = ((wx*viewm[2] + wy*viewm[6]) + wz*viewm[10]) + viewm[14];

    float fx = ((ndcx + 1.0f)*(float)Ww - 1.0f)*0.5f;
    float fy = ((ndcy + 1.0f)*(float)Hh - 1.0f)*0.5f;
    int ix = (int)rintf(fx);            // round half-to-even, like np.round
    int iy = (int)rintf(fy);
    bool valid = (depth > 0.2f) && (ix >= 0) && (ix < Ww) && (iy >= 0) && (iy < Hh);
    int pid = valid ? (iy*Ww + ix) : -1;

    // densities (8 floats, 32B aligned) + trivec mids (24 strided floats)
    float4 d0 = *(const float4*)(densities + (size_t)n*RR);
    float4 d1 = *(const float4*)(densities + (size_t)n*RR + 4);
    float den[8] = {d0.x,d0.y,d0.z,d0.w,d1.x,d1.y,d1.z,d1.w};
    const float* tv = trivecs + (size_t)n*RR*24;
    float sr[RR]; float sigma = 0.0f;
    #pragma unroll
    for (int r = 0; r < RR; r++){
        float m0 = tv[r*24 + 4];
        float m1 = tv[r*24 + 12];
        float m2 = tv[r*24 + 20];
        float tri = m0*m1*m2;
        tri = tri > 0.0f ? tri : 0.0f;
        float s = expf(den[r] - 2.0f) * tri;
        sr[r] = s; sigma += s;
    }
    float alpha = 1.0f - expf(-sigma);
    alpha = fminf(alpha, 0.999f);
    alpha = fmaxf(alpha, 0.0f);

    // SH basis from normalized view dir
    float dxr = wx - campos[0], dyr = wy - campos[1], dzr = wz - campos[2];
    float nrm = sqrtf((dxr*dxr + dyr*dyr) + dzr*dzr) + 1e-8f;
    float x = dxr/nrm, y = dyr/nrm, z = dzr/nrm;
    float basis[9];
    basis[0] = 0.28209479177387814f;
    basis[1] = -0.4886025119029199f * y;
    basis[2] =  0.4886025119029199f * z;
    basis[3] = -0.4886025119029199f * x;
    basis[4] =  1.0925484305920792f * (x*y);
    basis[5] = -1.0925484305920792f * (y*z);
    basis[6] =  0.31539156525252005f * (2.0f*z*z - x*x - y*y);
    basis[7] = -1.0925484305920792f * (x*z);
    basis[8] =  0.5462742152960396f * (x*x - y*y);

    // shs: 216 contiguous floats = 54 float4 (16B aligned), compile-time decode
    float dot[RR][3];
    #pragma unroll
    for (int r = 0; r < RR; r++){ dot[r][0]=0.f; dot[r][1]=0.f; dot[r][2]=0.f; }
    const float4* sp = (const float4*)(shs + (size_t)n*(RR*27));
    #pragma unroll
    for (int j = 0; j < 54; j++){
        float4 v = sp[j];
        float e[4] = {v.x, v.y, v.z, v.w};
        #pragma unroll
        for (int q = 0; q < 4; q++){
            int f = 4*j + q;
            int r = f / 27;
            int k = (f % 27) / 3;
            int c = f % 3;
            dot[r][c] = fmaf(basis[k], e[q], dot[r][c]);
        }
    }
    float invs = 1.0f/(sigma + 1e-8f);
    float cr = 0.f, cg = 0.f, cb = 0.f;
    #pragma unroll
    for (int r = 0; r < RR; r++){
        float wr = sr[r]*invs;
        cr = fmaf(wr, fmaxf(dot[r][0] + 0.5f, 0.0f), cr);
        cg = fmaf(wr, fmaxf(dot[r][1] + 0.5f, 0.0f), cg);
        cb = fmaf(wr, fmaxf(dot[r][2] + 0.5f, 0.0f), cb);
    }

    float4 ra = make_float4(depth, alpha, cr, cg);
    float4 rb = make_float4(cb, __int_as_float(n), __int_as_float(pid), 0.0f);
    float4* rp = (float4*)(recs + (size_t)n*8);
    rp[0] = ra; rp[1] = rb;
    if (pid >= 0) atomicAdd(&counts[pid], 1);
}

// ---- scan over HWW counts: 256 blocks x 1024 elems ----
__global__ __launch_bounds__(256) void scan1_kernel(const int* __restrict__ counts,
                                                    int* __restrict__ blockSums)
{
    __shared__ int lds[256];
    int b = blockIdx.x, t = threadIdx.x;
    int4 v = ((const int4*)(counts + (size_t)b*1024))[t];
    int s = v.x + v.y + v.z + v.w;
    lds[t] = s; __syncthreads();
    for (int off = 128; off > 0; off >>= 1){
        if (t < off) lds[t] += lds[t + off];
        __syncthreads();
    }
    if (t == 0) blockSums[b] = lds[0];
}

__global__ __launch_bounds__(256) void scan2_kernel(int* __restrict__ blockSums,
                                                    int* __restrict__ offsets)
{
    __shared__ int lds[256];
    int t = threadIdx.x;
    int v = blockSums[t];
    lds[t] = v; __syncthreads();
    #pragma unroll
    for (int off = 1; off < 256; off <<= 1){
        int add = (t >= off) ? lds[t - off] : 0;
        __syncthreads();
        lds[t] += add;
        __syncthreads();
    }
    blockSums[t] = lds[t] - v;              // exclusive block offset
    if (t == 255) offsets[HWW] = lds[255];  // total valid count
}

__global__ __launch_bounds__(256) void scan3_kernel(const int* __restrict__ counts,
                                                    const int* __restrict__ blockOffs,
                                                    int* __restrict__ offsets,
                                                    int* __restrict__ cursor)
{
    __shared__ int lds[256];
    int b = blockIdx.x, t = threadIdx.x;
    int4 v = ((const int4*)(counts + (size_t)b*1024))[t];
    int s = v.x + v.y + v.z + v.w;
    lds[t] = s; __syncthreads();
    #pragma unroll
    for (int off = 1; off < 256; off <<= 1){
        int add = (t >= off) ? lds[t - off] : 0;
        __syncthreads();
        lds[t] += add;
        __syncthreads();
    }
    int base = blockOffs[b] + (lds[t] - s);
    int4 o;
    o.x = base;
    o.y = o.x + v.x;
    o.z = o.y + v.y;
    o.w = o.z + v.z;
    ((int4*)(offsets + (size_t)b*1024))[t] = o;
    ((int4*)(cursor  + (size_t)b*1024))[t] = o;
}

__global__ __launch_bounds__(256) void scatter_kernel(const float* __restrict__ recs,
                                                      int* __restrict__ cursor,
                                                      float* __restrict__ srecs)
{
    int n = blockIdx.x * blockDim.x + threadIdx.x;
    if (n >= NP) return;
    const float4* rp = (const float4*)(recs + (size_t)n*8);
    float4 ra = rp[0], rb = rp[1];
    int pid = __float_as_int(rb.z);
    if (pid < 0) return;
    int slot = atomicAdd(&cursor[pid], 1);
    float4* sp = (float4*)(srecs + (size_t)slot*8);
    sp[0] = ra; sp[1] = rb;
}

__global__ __launch_bounds__(256) void composite_kernel(const int* __restrict__ offsets,
                                                        const float* __restrict__ srecs,
                                                        const float* __restrict__ bg,
                                                        float* __restrict__ out)
{
    int p = blockIdx.x * blockDim.x + threadIdx.x;
    if (p >= HWW) return;
    int s = offsets[p], e = offsets[p+1];
    float T = 1.0f, accA = 0.f, accD = 0.f, aR = 0.f, aG = 0.f, aB = 0.f;
    float lastD = -FLT_MAX; int lastI = -1;
    for (int it = s; it < e; ++it){
        // select min (depth, idx) strictly greater than (lastD, lastI)
        float bd = FLT_MAX; int bi = 0x7fffffff; int bj = -1;
        for (int j = s; j < e; ++j){
            float4 ra = *(const float4*)(srecs + (size_t)j*8);
            float4 rb = *(const float4*)(srecs + (size_t)j*8 + 4);
            float dj = ra.x; int ij = __float_as_int(rb.y);
            bool gt = (dj > lastD) || (dj == lastD && ij > lastI);
            bool lt = (dj < bd)   || (dj == bd   && ij < bi);
            if (gt && lt){ bd = dj; bi = ij; bj = j; }
        }
        float4 ra = *(const float4*)(srecs + (size_t)bj*8);
        float4 rb = *(const float4*)(srecs + (size_t)bj*8 + 4);
        float a = ra.y;
        float w = a*T;
        aR += w*ra.z; aG += w*ra.w; aB += w*rb.x;
        accA += w; accD += w*ra.x;
        T *= (1.0f - a);
        lastD = bd; lastI = bi;
    }
    float om = 1.0f - accA;
    out[p]         = aR + om*bg[0];
    out[HWW + p]   = aG + om*bg[1];
    out[2*HWW + p] = aB + om*bg[2];
    out[3*HWW + p] = accD;
    out[4*HWW + p] = accA;
    out[5*HWW + p] = accD/(accA + 1e-8f);
}

extern "C" void kernel_launch(void* const* d_in, const int* in_sizes, int n_in,
                              void* d_out, int out_size, void* d_ws, size_t ws_size,
                              hipStream_t stream)
{
    const float* positions = (const float*)d_in[0];
    const float* trivecs   = (const float*)d_in[1];
    const float* densities = (const float*)d_in[2];
    const float* shs       = (const float*)d_in[3];
    const float* viewm     = (const float*)d_in[4];
    const float* projm     = (const float*)d_in[5];
    const float* campos    = (const float*)d_in[6];
    const float* aabb      = (const float*)d_in[7];
    const float* bg        = (const float*)d_in[8];
    float* out = (float*)d_out;

    char* ws = (char*)d_ws;
    size_t o = 0;
    int* counts    = (int*)(ws + o); o += (size_t)HWW*4;
    int* offsets   = (int*)(ws + o); o += ((size_t)HWW + 64)*4;
    int* cursor    = (int*)(ws + o); o += (size_t)HWW*4;
    int* blockSums = (int*)(ws + o); o += 4096;
    float* recs    = (float*)(ws + o); o += (size_t)NP*32;
    float* srecs   = (float*)(ws + o); o += (size_t)NP*32;

    hipMemsetAsync(counts, 0, (size_t)HWW*4, stream);
    point_kernel<<<NP/256, 256, 0, stream>>>(positions, trivecs, densities, shs,
                                             viewm, projm, campos, aabb, recs, counts);
    scan1_kernel<<<HWW/1024, 256, 0, stream>>>(counts, blockSums);
    scan2_kernel<<<1, 256, 0, stream>>>(blockSums, offsets);
    scan3_kernel<<<HWW/1024, 256, 0, stream>>>(counts, blockSums, offsets, cursor);
    scatter_kernel<<<NP/256, 256, 0, stream>>>(recs, cursor, srecs);
    composite_kernel<<<HWW/256, 256, 0, stream>>>(offsets, srecs, bg, out);
}

// Round 2
// 510.231 us; speedup vs baseline: 1.0802x; 1.0802x over previous
//
#include <hip/hip_runtime.h>
#include <math.h>
#include <float.h>

#define Hh 512
#define Ww 512
#define HWW (Hh*Ww)
#define NP 262144
#define RR 8
#define KMAX 32

// Record per point: 8 floats = 32B: {depth, alpha, r, g | b, next(bits), 0, 0}
// Ordering key = (depth_bits << 32) | point_idx  -- matches lexsort((depth,pid))
// within-pixel order: ascending depth, ties by original index (depth>0 so
// float bits are monotonic).

__global__ __launch_bounds__(256) void point_kernel(
    const float* __restrict__ positions,
    const float* __restrict__ trivecs,
    const float* __restrict__ densities,
    const float* __restrict__ shs,
    const float* __restrict__ viewm,
    const float* __restrict__ projm,
    const float* __restrict__ campos,
    const float* __restrict__ aabb,
    float* __restrict__ recs,
    int* __restrict__ heads)
{
#pragma clang fp contract(off)
    int gid = blockIdx.x * blockDim.x + threadIdx.x;   // 2*NP threads
    int n    = gid >> 1;
    int half = gid & 1;

    float px = positions[n*3+0], py = positions[n*3+1], pz = positions[n*3+2];
    float wx = aabb[0] + px*aabb[3];
    float wy = aabb[1] + py*aabb[4];
    float wz = aabb[2] + pz*aabb[5];

    float phx = ((wx*projm[0] + wy*projm[4]) + wz*projm[8])  + projm[12];
    float phy = ((wx*projm[1] + wy*projm[5]) + wz*projm[9])  + projm[13];
    float phw = ((wx*projm[3] + wy*projm[7]) + wz*projm[11]) + projm[15];
    float denom = phw + 1e-7f;
    float ndcx = phx / denom;
    float ndcy = phy / denom;
    float depth = ((wx*viewm[2] + wy*viewm[6]) + wz*viewm[10]) + viewm[14];

    float fx = ((ndcx + 1.0f)*(float)Ww - 1.0f)*0.5f;
    float fy = ((ndcy + 1.0f)*(float)Hh - 1.0f)*0.5f;
    int ix = (int)rintf(fx);
    int iy = (int)rintf(fy);
    bool valid = (depth > 0.2f) && (ix >= 0) && (ix < Ww) && (iy >= 0) && (iy < Hh);
    int pid = valid ? (iy*Ww + ix) : -1;

    // this thread's 4 ranks: r = half*4 .. half*4+3
    float4 d = *(const float4*)(densities + (size_t)n*RR + half*4);
    float den[4] = {d.x, d.y, d.z, d.w};
    const float* tv = trivecs + (size_t)n*RR*24 + half*4*24;
    float sr[4]; float sig_half = 0.0f;
    #pragma unroll
    for (int r = 0; r < 4; r++){
        float m0 = tv[r*24 + 4];
        float m1 = tv[r*24 + 12];
        float m2 = tv[r*24 + 20];
        float tri = m0*m1*m2;
        tri = tri > 0.0f ? tri : 0.0f;
        float s = expf(den[r] - 2.0f) * tri;
        sr[r] = s; sig_half += s;
    }
    float sigma = sig_half + __shfl_xor(sig_half, 1, 64);
    float alpha = 1.0f - expf(-sigma);
    alpha = fminf(alpha, 0.999f);
    alpha = fmaxf(alpha, 0.0f);

    // SH basis (redundant per pair; VALU is nearly idle)
    float dxr = wx - campos[0], dyr = wy - campos[1], dzr = wz - campos[2];
    float nrm = sqrtf((dxr*dxr + dyr*dyr) + dzr*dzr) + 1e-8f;
    float x = dxr/nrm, y = dyr/nrm, z = dzr/nrm;
    float basis[9];
    basis[0] = 0.28209479177387814f;
    basis[1] = -0.4886025119029199f * y;
    basis[2] =  0.4886025119029199f * z;
    basis[3] = -0.4886025119029199f * x;
    basis[4] =  1.0925484305920792f * (x*y);
    basis[5] = -1.0925484305920792f * (y*z);
    basis[6] =  0.31539156525252005f * (2.0f*z*z - x*x - y*y);
    basis[7] = -1.0925484305920792f * (x*z);
    basis[8] =  0.5462742152960396f * (x*x - y*y);

    // this thread's shs slice: 108 floats = 27 float4 (432B-aligned offset)
    float dot[4][3];
    #pragma unroll
    for (int r = 0; r < 4; r++){ dot[r][0]=0.f; dot[r][1]=0.f; dot[r][2]=0.f; }
    const float4* sp = (const float4*)(shs + (size_t)n*(RR*27)) + half*27;
    #pragma unroll
    for (int j = 0; j < 27; j++){
        float4 v = sp[j];
        float e[4] = {v.x, v.y, v.z, v.w};
        #pragma unroll
        for (int q = 0; q < 4; q++){
            int f = 4*j + q;          // 0..107 within this half
            int r = f / 27;           // local rank 0..3 (compile-time)
            int k = (f % 27) / 3;
            int c = f % 3;
            dot[r][c] = fmaf(basis[k], e[q], dot[r][c]);
        }
    }
    float invs = 1.0f/(sigma + 1e-8f);
    float cr = 0.f, cg = 0.f, cb = 0.f;
    #pragma unroll
    for (int r = 0; r < 4; r++){
        float wr = sr[r]*invs;
        cr = fmaf(wr, fmaxf(dot[r][0] + 0.5f, 0.0f), cr);
        cg = fmaf(wr, fmaxf(dot[r][1] + 0.5f, 0.0f), cg);
        cb = fmaf(wr, fmaxf(dot[r][2] + 0.5f, 0.0f), cb);
    }
    cr += __shfl_xor(cr, 1, 64);
    cg += __shfl_xor(cg, 1, 64);
    cb += __shfl_xor(cb, 1, 64);

    if (half == 0 && pid >= 0){
        int next = atomicExch(&heads[pid], n);
        float4* rp = (float4*)(recs + (size_t)n*8);
        rp[0] = make_float4(depth, alpha, cr, cg);
        rp[1] = make_float4(cb, __int_as_float(next), 0.0f, 0.0f);
    }
}

__global__ __launch_bounds__(256) void composite_kernel(
    const int* __restrict__ heads,
    const float* __restrict__ recs,
    const float* __restrict__ bg,
    float* __restrict__ out)
{
    int p = blockIdx.x * blockDim.x + threadIdx.x;
    if (p >= HWW) return;

    unsigned long long keys[KMAX];
    int cnt = 0;
    int cur = heads[p];
    while (cur >= 0){
        float dpt = recs[(size_t)cur*8 + 0];
        int  nxt  = __float_as_int(recs[(size_t)cur*8 + 5]);
        if (cnt < KMAX)
            keys[cnt] = ((unsigned long long)__float_as_uint(dpt) << 32) |
                        (unsigned int)cur;
        cnt++;
        cur = nxt;
    }

    float T = 1.0f, accA = 0.f, accD = 0.f, aR = 0.f, aG = 0.f, aB = 0.f;

    if (cnt <= KMAX){
        // insertion sort ascending by (depth_bits, idx)
        for (int i = 1; i < cnt; i++){
            unsigned long long k = keys[i];
            int j = i - 1;
            while (j >= 0 && keys[j] > k){ keys[j+1] = keys[j]; j--; }
            keys[j+1] = k;
        }
        for (int i = 0; i < cnt; i++){
            int nidx = (int)(keys[i] & 0xffffffffu);
            float4 ra = *(const float4*)(recs + (size_t)nidx*8);
            float4 rb = *(const float4*)(recs + (size_t)nidx*8 + 4);
            float a = ra.y, w = a*T;
            aR += w*ra.z; aG += w*ra.w; aB += w*rb.x;
            accA += w; accD += w*ra.x;
            T *= (1.0f - a);
        }
    } else {
        // overflow fallback (statistically unreachable): repeated selection
        unsigned long long last = 0; bool haveLast = false;
        for (int it = 0; it < cnt; ++it){
            unsigned long long best = ~0ull; int bn = -1;
            for (int c2 = heads[p]; c2 >= 0; ){
                float dpt = recs[(size_t)c2*8 + 0];
                int  nxt  = __float_as_int(recs[(size_t)c2*8 + 5]);
                unsigned long long k =
                    ((unsigned long long)__float_as_uint(dpt) << 32) |
                    (unsigned int)c2;
                if ((!haveLast || k > last) && k < best){ best = k; bn = c2; }
                c2 = nxt;
            }
            float4 ra = *(const float4*)(recs + (size_t)bn*8);
            float4 rb = *(const float4*)(recs + (size_t)bn*8 + 4);
            float a = ra.y, w = a*T;
            aR += w*ra.z; aG += w*ra.w; aB += w*rb.x;
            accA += w; accD += w*ra.x;
            T *= (1.0f - a);
            last = best; haveLast = true;
        }
    }

    float om = 1.0f - accA;
    out[p]         = aR + om*bg[0];
    out[HWW + p]   = aG + om*bg[1];
    out[2*HWW + p] = aB + om*bg[2];
    out[3*HWW + p] = accD;
    out[4*HWW + p] = accA;
    out[5*HWW + p] = accD/(accA + 1e-8f);
}

extern "C" void kernel_launch(void* const* d_in, const int* in_sizes, int n_in,
                              void* d_out, int out_size, void* d_ws, size_t ws_size,
                              hipStream_t stream)
{
    const float* positions = (const float*)d_in[0];
    const float* trivecs   = (const float*)d_in[1];
    const float* densities = (const float*)d_in[2];
    const float* shs       = (const float*)d_in[3];
    const float* viewm     = (const float*)d_in[4];
    const float* projm     = (const float*)d_in[5];
    const float* campos    = (const float*)d_in[6];
    const float* aabb      = (const float*)d_in[7];
    const float* bg        = (const float*)d_in[8];
    float* out = (float*)d_out;

    char* ws = (char*)d_ws;
    size_t o = 0;
    int*   heads = (int*)(ws + o);   o += (size_t)HWW*4;
    float* recs  = (float*)(ws + o); o += (size_t)NP*32;

    hipMemsetAsync(heads, 0xFF, (size_t)HWW*4, stream);   // all -1
    point_kernel<<<(NP*2)/256, 256, 0, stream>>>(positions, trivecs, densities, shs,
                                                 viewm, projm, campos, aabb,
                                                 recs, heads);
    composite_kernel<<<HWW/256, 256, 0, stream>>>(heads, recs, bg, out);
}

// Round 3
// 500.963 us; speedup vs baseline: 1.1002x; 1.0185x over previous
//
#include <hip/hip_runtime.h>
#include <math.h>
#include <float.h>

#define Hh 512
#define Ww 512
#define HWW (Hh*Ww)
#define NP 262144
#define KMAX 16

// Record per point: 8 floats = 32B: {depth, next(bits), alpha, r | g, b, -, -}
// Walk needs only the leading float2 {depth, next}.
// Ordering key = (depth_bits << 32) | point_idx  (depth > 0.2 -> bits monotonic),
// matching lexsort((depth, pid)) with stable tie-break by original index.

__device__ __forceinline__ unsigned long long umin64(unsigned long long a,
                                                     unsigned long long b){
    return a < b ? a : b;
}

__global__ __launch_bounds__(256) void point_kernel(
    const float* __restrict__ positions,
    const float* __restrict__ trivecs,
    const float* __restrict__ densities,
    const float* __restrict__ shs,
    const float* __restrict__ viewm,
    const float* __restrict__ projm,
    const float* __restrict__ campos,
    const float* __restrict__ aabb,
    float* __restrict__ recs,
    int* __restrict__ heads)
{
#pragma clang fp contract(off)
    int gid = blockIdx.x * blockDim.x + threadIdx.x;   // 2*NP threads
    int n    = gid >> 1;
    int half = gid & 1;

    // ---------- issue ALL global loads up front (max MLP) ----------
    float px = positions[n*3+0], py = positions[n*3+1], pz = positions[n*3+2];

    float4 dv = *(const float4*)(densities + (size_t)n*8 + half*4);

    const float* tv = trivecs + (size_t)n*192 + half*96;
    float tvm[12];
    #pragma unroll
    for (int r = 0; r < 4; r++){
        tvm[r*3+0] = tv[r*24 + 4];
        tvm[r*3+1] = tv[r*24 + 12];
        tvm[r*3+2] = tv[r*24 + 20];
    }

    const float4* sp = (const float4*)(shs + (size_t)n*216) + half*27;
    float4 sh[27];
    #pragma unroll
    for (int j = 0; j < 27; j++) sh[j] = sp[j];

    // ---------- geometry ----------
    float wx = aabb[0] + px*aabb[3];
    float wy = aabb[1] + py*aabb[4];
    float wz = aabb[2] + pz*aabb[5];

    float phx = ((wx*projm[0] + wy*projm[4]) + wz*projm[8])  + projm[12];
    float phy = ((wx*projm[1] + wy*projm[5]) + wz*projm[9])  + projm[13];
    float phw = ((wx*projm[3] + wy*projm[7]) + wz*projm[11]) + projm[15];
    float denom = phw + 1e-7f;
    float ndcx = phx / denom;
    float ndcy = phy / denom;
    float depth = ((wx*viewm[2] + wy*viewm[6]) + wz*viewm[10]) + viewm[14];

    float fx = ((ndcx + 1.0f)*(float)Ww - 1.0f)*0.5f;
    float fy = ((ndcy + 1.0f)*(float)Hh - 1.0f)*0.5f;
    int ix = (int)rintf(fx);
    int iy = (int)rintf(fy);
    bool valid = (depth > 0.2f) && (ix >= 0) && (ix < Ww) && (iy >= 0) && (iy < Hh);
    int pid = valid ? (iy*Ww + ix) : -1;

    // ---------- density / alpha ----------
    float den[4] = {dv.x, dv.y, dv.z, dv.w};
    float sr[4]; float sig_half = 0.0f;
    #pragma unroll
    for (int r = 0; r < 4; r++){
        float tri = tvm[r*3+0]*tvm[r*3+1]*tvm[r*3+2];
        tri = tri > 0.0f ? tri : 0.0f;
        float s = expf(den[r] - 2.0f) * tri;
        sr[r] = s; sig_half += s;
    }
    float sigma = sig_half + __shfl_xor(sig_half, 1, 64);
    float alpha = 1.0f - expf(-sigma);
    alpha = fminf(alpha, 0.999f);
    alpha = fmaxf(alpha, 0.0f);

    // ---------- SH color ----------
    float dxr = wx - campos[0], dyr = wy - campos[1], dzr = wz - campos[2];
    float nrm = sqrtf((dxr*dxr + dyr*dyr) + dzr*dzr) + 1e-8f;
    float x = dxr/nrm, y = dyr/nrm, z = dzr/nrm;
    float basis[9];
    basis[0] = 0.28209479177387814f;
    basis[1] = -0.4886025119029199f * y;
    basis[2] =  0.4886025119029199f * z;
    basis[3] = -0.4886025119029199f * x;
    basis[4] =  1.0925484305920792f * (x*y);
    basis[5] = -1.0925484305920792f * (y*z);
    basis[6] =  0.31539156525252005f * (2.0f*z*z - x*x - y*y);
    basis[7] = -1.0925484305920792f * (x*z);
    basis[8] =  0.5462742152960396f * (x*x - y*y);

    float dot[4][3];
    #pragma unroll
    for (int r = 0; r < 4; r++){ dot[r][0]=0.f; dot[r][1]=0.f; dot[r][2]=0.f; }
    #pragma unroll
    for (int j = 0; j < 27; j++){
        float e[4] = {sh[j].x, sh[j].y, sh[j].z, sh[j].w};
        #pragma unroll
        for (int q = 0; q < 4; q++){
            int f = 4*j + q;          // 0..107 within this half
            int r = f / 27;           // local rank 0..3 (compile-time)
            int k = (f % 27) / 3;
            int c = f % 3;
            dot[r][c] = fmaf(basis[k], e[q], dot[r][c]);
        }
    }
    float invs = 1.0f/(sigma + 1e-8f);
    float cr = 0.f, cg = 0.f, cb = 0.f;
    #pragma unroll
    for (int r = 0; r < 4; r++){
        float wr = sr[r]*invs;
        cr = fmaf(wr, fmaxf(dot[r][0] + 0.5f, 0.0f), cr);
        cg = fmaf(wr, fmaxf(dot[r][1] + 0.5f, 0.0f), cg);
        cb = fmaf(wr, fmaxf(dot[r][2] + 0.5f, 0.0f), cb);
    }
    cr += __shfl_xor(cr, 1, 64);
    cg += __shfl_xor(cg, 1, 64);
    cb += __shfl_xor(cb, 1, 64);

    if (half == 0 && pid >= 0){
        int next = atomicExch(&heads[pid], n);
        float4* rp = (float4*)(recs + (size_t)n*8);
        rp[0] = make_float4(depth, __int_as_float(next), alpha, cr);
        *(float2*)(recs + (size_t)n*8 + 4) = make_float2(cg, cb);
    }
}

__global__ __launch_bounds__(256) void composite_kernel(
    const int* __restrict__ heads,
    const float* __restrict__ recs,
    const float* __restrict__ bg,
    float* __restrict__ out)
{
    int p = blockIdx.x * blockDim.x + threadIdx.x;
    if (p >= HWW) return;

    const unsigned long long NONE = ~0ull;
    unsigned long long keys[KMAX];
    int cur = heads[p];

    // scratch-free walk: fully unrolled, compile-time indices only
    #pragma unroll
    for (int i = 0; i < KMAX; i++){
        unsigned long long k = NONE;
        if (cur >= 0){
            float2 dn = *(const float2*)(recs + (size_t)cur*8);
            k = ((unsigned long long)__float_as_uint(dn.x) << 32) |
                (unsigned int)cur;
            cur = __float_as_int(dn.y);
        }
        keys[i] = k;
    }
    bool overflow = (cur >= 0);

    float T = 1.0f, accA = 0.f, accD = 0.f, aR = 0.f, aG = 0.f, aB = 0.f;

    if (!overflow){
        for (int it = 0; it < KMAX; ++it){
            // tree min over keys[] — all compile-time indices
            unsigned long long m0 = umin64(keys[0],  keys[1]);
            unsigned long long m1 = umin64(keys[2],  keys[3]);
            unsigned long long m2 = umin64(keys[4],  keys[5]);
            unsigned long long m3 = umin64(keys[6],  keys[7]);
            unsigned long long m4 = umin64(keys[8],  keys[9]);
            unsigned long long m5 = umin64(keys[10], keys[11]);
            unsigned long long m6 = umin64(keys[12], keys[13]);
            unsigned long long m7 = umin64(keys[14], keys[15]);
            m0 = umin64(m0, m1); m2 = umin64(m2, m3);
            m4 = umin64(m4, m5); m6 = umin64(m6, m7);
            m0 = umin64(m0, m2); m4 = umin64(m4, m6);
            unsigned long long m = umin64(m0, m4);

            if (!__any(m != NONE)) break;   // wave-uniform early exit

            if (m != NONE){
                int nidx = (int)(m & 0xffffffffu);
                float4 ra = *(const float4*)(recs + (size_t)nidx*8);
                float2 rb = *(const float2*)(recs + (size_t)nidx*8 + 4);
                float a = ra.z, w = a*T;
                aR += w*ra.w; aG += w*rb.x; aB += w*rb.y;
                accA += w; accD += w*ra.x;
                T *= (1.0f - a);
                #pragma unroll
                for (int j = 0; j < KMAX; j++)
                    keys[j] = (keys[j] == m) ? NONE : keys[j];
            }
        }
    } else {
        // statistically-unreachable overflow: exact selection over the list
        unsigned long long last = 0; bool haveLast = false;
        for (;;){
            unsigned long long best = NONE;
            for (int c2 = heads[p]; c2 >= 0; ){
                float2 dn = *(const float2*)(recs + (size_t)c2*8);
                unsigned long long k =
                    ((unsigned long long)__float_as_uint(dn.x) << 32) |
                    (unsigned int)c2;
                if ((!haveLast || k > last) && k < best) best = k;
                c2 = __float_as_int(dn.y);
            }
            if (best == NONE) break;
            int nidx = (int)(best & 0xffffffffu);
            float4 ra = *(const float4*)(recs + (size_t)nidx*8);
            float2 rb = *(const float2*)(recs + (size_t)nidx*8 + 4);
            float a = ra.z, w = a*T;
            aR += w*ra.w; aG += w*rb.x; aB += w*rb.y;
            accA += w; accD += w*ra.x;
            T *= (1.0f - a);
            last = best; haveLast = true;
        }
    }

    float om = 1.0f - accA;
    out[p]         = aR + om*bg[0];
    out[HWW + p]   = aG + om*bg[1];
    out[2*HWW + p] = aB + om*bg[2];
    out[3*HWW + p] = accD;
    out[4*HWW + p] = accA;
    out[5*HWW + p] = accD/(accA + 1e-8f);
}

extern "C" void kernel_launch(void* const* d_in, const int* in_sizes, int n_in,
                              void* d_out, int out_size, void* d_ws, size_t ws_size,
                              hipStream_t stream)
{
    const float* positions = (const float*)d_in[0];
    const float* trivecs   = (const float*)d_in[1];
    const float* densities = (const float*)d_in[2];
    const float* shs       = (const float*)d_in[3];
    const float* viewm     = (const float*)d_in[4];
    const float* projm     = (const float*)d_in[5];
    const float* campos    = (const float*)d_in[6];
    const float* aabb      = (const float*)d_in[7];
    const float* bg        = (const float*)d_in[8];
    float* out = (float*)d_out;

    char* ws = (char*)d_ws;
    size_t o = 0;
    int*   heads = (int*)(ws + o);   o += (size_t)HWW*4;
    float* recs  = (float*)(ws + o); o += (size_t)NP*32;

    hipMemsetAsync(heads, 0xFF, (size_t)HWW*4, stream);   // all -1
    point_kernel<<<(NP*2)/256, 256, 0, stream>>>(positions, trivecs, densities, shs,
                                                 viewm, projm, campos, aabb,
                                                 recs, heads);
    composite_kernel<<<HWW/256, 256, 0, stream>>>(heads, recs, bg, out);
}